// Round 2
// baseline (1112.390 us; speedup 1.0000x reference)
//
#include <hip/hip_runtime.h>
#include <hip/hip_bf16.h>

// Problem constants (from reference): N=8192, D=128, NUM_CLASSES=1000
#define CN 8192
#define CD 128
#define NCLS 1000
#define BM 64
#define BN 64
#define LDP 132  // padded LDS leading dim (132*4B = 33*16B, keeps float4 alignment, breaks pow2 bank stride)

__global__ void hist_kernel(const int* __restrict__ targets, int* __restrict__ hist) {
    int i = blockIdx.x * blockDim.x + threadIdx.x;
    if (i < CN) atomicAdd(&hist[targets[i]], 1);
}

// One block = 64 rows of direction `blockIdx.y`; sweeps all 8192 columns.
// Row-wise accumulators (sum of exp(s-T), sum of eq*s) live in registers.
__global__ __launch_bounds__(256) void contrastive_kernel(
    const float* __restrict__ Tptr,
    const float* __restrict__ fa,
    const float* __restrict__ fb,
    const int* __restrict__ targets,
    const int* __restrict__ hist,
    float* __restrict__ out)
{
    __shared__ float sA[BM][LDP];
    __shared__ float sB[BN][LDP];
    __shared__ int   sTc[BN];
    __shared__ float red[4];

    const int tid  = threadIdx.x;
    const int dir  = blockIdx.y;            // 0: rows=fa cols=fb ; 1: rows=fb cols=fa
    const float* A = dir == 0 ? fa : fb;
    const float* B = dir == 0 ? fb : fa;
    const int brow = blockIdx.x * BM;
    const float Tval = Tptr[0];

    // ---- stage the 64 A-rows once ----
    for (int idx = tid; idx < BM * (CD / 4); idx += 256) {
        int r  = idx / (CD / 4);
        int c4 = idx % (CD / 4);
        float4 v = reinterpret_cast<const float4*>(A + (size_t)(brow + r) * CD)[c4];
        sA[r][c4 * 4 + 0] = v.x; sA[r][c4 * 4 + 1] = v.y;
        sA[r][c4 * 4 + 2] = v.z; sA[r][c4 * 4 + 3] = v.w;
    }

    const int ty = tid >> 4;     // 0..15 row group  (4 rows each)
    const int tx = tid & 15;     // 0..15 col group  (4 cols each)
    const int r0 = ty * 4;
    const int c0 = tx * 4;

    int tRow[4];
    #pragma unroll
    for (int rr = 0; rr < 4; rr++) tRow[rr] = targets[brow + r0 + rr];

    float sumexp[4] = {0.f, 0.f, 0.f, 0.f};
    float eqS[4]    = {0.f, 0.f, 0.f, 0.f};

    for (int jt = 0; jt < CN; jt += BN) {
        __syncthreads();
        // stage B tile + its targets
        for (int idx = tid; idx < BN * (CD / 4); idx += 256) {
            int r  = idx / (CD / 4);
            int c4 = idx % (CD / 4);
            float4 v = reinterpret_cast<const float4*>(B + (size_t)(jt + r) * CD)[c4];
            sB[r][c4 * 4 + 0] = v.x; sB[r][c4 * 4 + 1] = v.y;
            sB[r][c4 * 4 + 2] = v.z; sB[r][c4 * 4 + 3] = v.w;
        }
        if (tid < BN) sTc[tid] = targets[jt + tid];
        __syncthreads();

        float acc[4][4] = {};
        #pragma unroll 4
        for (int k = 0; k < CD; k += 4) {
            float4 a[4], b[4];
            #pragma unroll
            for (int rr = 0; rr < 4; rr++) a[rr] = *reinterpret_cast<const float4*>(&sA[r0 + rr][k]);
            #pragma unroll
            for (int cc = 0; cc < 4; cc++) b[cc] = *reinterpret_cast<const float4*>(&sB[c0 + cc][k]);
            #pragma unroll
            for (int rr = 0; rr < 4; rr++)
                #pragma unroll
                for (int cc = 0; cc < 4; cc++)
                    acc[rr][cc] += a[rr].x * b[cc].x + a[rr].y * b[cc].y
                                 + a[rr].z * b[cc].z + a[rr].w * b[cc].w;
        }

        // epilogue: fold this 4x4 micro-tile into row accumulators
        #pragma unroll
        for (int rr = 0; rr < 4; rr++) {
            #pragma unroll
            for (int cc = 0; cc < 4; cc++) {
                float d = acc[rr][cc];
                // exp(s - T) with s = T*d  ->  exp(T*(d-1)); |cos|<=1 so arg <= 0
                sumexp[rr] += __expf(Tval * (d - 1.0f));
                if (tRow[rr] == sTc[c0 + cc]) eqS[rr] += Tval * d;
            }
        }
    }

    // reduce across the 16 col-groups (tx occupies low 4 lane bits)
    #pragma unroll
    for (int off = 1; off < 16; off <<= 1) {
        #pragma unroll
        for (int rr = 0; rr < 4; rr++) {
            sumexp[rr] += __shfl_xor(sumexp[rr], off);
            eqS[rr]    += __shfl_xor(eqS[rr], off);
        }
    }

    float local = 0.f;
    if (tx == 0) {
        #pragma unroll
        for (int rr = 0; rr < 4; rr++) {
            int row = brow + r0 + rr;
            float tsum = (float)hist[targets[row]];
            // per_row = -eqS/tsum + lse,  lse = T + log(sum exp(s-T))
            local += -eqS[rr] / tsum + Tval + logf(sumexp[rr]);
        }
    }
    // wave reduce (only tx==0 lanes hold nonzero), then block reduce
    #pragma unroll
    for (int off = 1; off < 64; off <<= 1) local += __shfl_xor(local, off);

    const int wave = tid >> 6;
    if ((tid & 63) == 0) red[wave] = local;
    __syncthreads();
    if (tid == 0) {
        float tot = red[0] + red[1] + red[2] + red[3];
        atomicAdd(out, tot * (1.0f / (2.0f * (float)CN)));
    }
}

extern "C" void kernel_launch(void* const* d_in, const int* in_sizes, int n_in,
                              void* d_out, int out_size, void* d_ws, size_t ws_size,
                              hipStream_t stream) {
    const float* T   = (const float*)d_in[0];
    const float* fa  = (const float*)d_in[1];
    const float* fb  = (const float*)d_in[2];
    const int* tgt   = (const int*)d_in[3];
    float* out       = (float*)d_out;
    int* hist        = (int*)d_ws;

    hipMemsetAsync(out, 0, sizeof(float), stream);
    hipMemsetAsync(hist, 0, NCLS * sizeof(int), stream);

    hist_kernel<<<CN / 256, 256, 0, stream>>>(tgt, hist);

    dim3 grid(CN / BM, 2);
    contrastive_kernel<<<grid, 256, 0, stream>>>(T, fa, fb, tgt, hist, out);
}

// Round 3
// 203.002 us; speedup vs baseline: 5.4797x; 5.4797x over previous
//
#include <hip/hip_runtime.h>
#include <hip/hip_bf16.h>

// N=8192, D=128, NUM_CLASSES=1000
#define CN 8192
#define CD 128
#define NCLS 1000

typedef __attribute__((ext_vector_type(8))) short bf16x8;
typedef __attribute__((ext_vector_type(4))) float f32x4;

// ---- ws layout (bytes) ----
// [0x000000) Abf : CN*CD bf16 = 2 MB
// [0x200000) Bbf : 2 MB
// [0x400000) hist: 1000 int (pad to 4 KB)
// [0x401000) rowE, [0x409000) rowQ, [0x411000) colE, [0x419000) colQ : 32 KB each
#define WS_B_OFF    0x200000u
#define WS_HIST_OFF 0x400000u
#define WS_ROWE_OFF 0x401000u
#define WS_ROWQ_OFF 0x409000u
#define WS_COLE_OFF 0x411000u
#define WS_COLQ_OFF 0x419000u
#define WS_ZERO_BYTES 0x21000u   // hist + 4 accumulator arrays

__device__ inline unsigned short f2bf(float f) {
    unsigned int u = __float_as_uint(f);
    unsigned int r = (u + 0x7FFFu + ((u >> 16) & 1u)) >> 16;   // RNE
    return (unsigned short)r;
}

__global__ void convert_kernel(const float* __restrict__ fa, const float* __restrict__ fb,
                               unsigned short* __restrict__ Abf, unsigned short* __restrict__ Bbf) {
    const float* src = blockIdx.y == 0 ? fa : fb;
    unsigned short* dst = blockIdx.y == 0 ? Abf : Bbf;
    int i = (blockIdx.x * 256 + threadIdx.x) * 4;
    float4 v = *reinterpret_cast<const float4*>(src + i);
    ushort4 o;
    o.x = f2bf(v.x); o.y = f2bf(v.y); o.z = f2bf(v.z); o.w = f2bf(v.w);
    *reinterpret_cast<ushort4*>(dst + i) = o;
}

__global__ void hist_kernel(const int* __restrict__ targets, int* __restrict__ hist) {
    int i = blockIdx.x * blockDim.x + threadIdx.x;
    if (i < CN) atomicAdd(&hist[targets[i]], 1);
}

// One 128x128 tile of S = T*(fa . fb^T). Row partials -> direction i,
// col partials -> direction t (eq mask is symmetric). One barrier per block.
__global__ __launch_bounds__(256) void tile_kernel(
    const float* __restrict__ Tptr,
    const unsigned short* __restrict__ Abf,
    const unsigned short* __restrict__ Bbf,
    const int* __restrict__ targets,
    float* __restrict__ rowE_g, float* __restrict__ rowQ_g,
    float* __restrict__ colE_g, float* __restrict__ colQ_g)
{
    __shared__ __align__(16) unsigned short sA[128 * 128];
    __shared__ __align__(16) unsigned short sB[128 * 128];
    __shared__ int sTa[128];
    __shared__ int sTb[128];

    const int tid  = threadIdx.x;
    const int brow = blockIdx.y * 128;
    const int bcol = blockIdx.x * 128;
    const float T  = Tptr[0];

    // ---- stage both tiles, XOR-swizzled 16B slots: slot' = slot ^ (row&7) ----
    #pragma unroll
    for (int it = 0; it < 8; ++it) {
        int idx = it * 256 + tid;
        int r = idx >> 4, s = idx & 15;
        int sw = s ^ (r & 7);
        float4 va = *reinterpret_cast<const float4*>(Abf + (size_t)(brow + r) * CD + s * 8);
        *reinterpret_cast<float4*>(&sA[r * 128 + sw * 8]) = va;
        float4 vb = *reinterpret_cast<const float4*>(Bbf + (size_t)(bcol + r) * CD + s * 8);
        *reinterpret_cast<float4*>(&sB[r * 128 + sw * 8]) = vb;
    }
    if (tid < 128) sTa[tid] = targets[brow + tid];
    else           sTb[tid - 128] = targets[bcol + (tid - 128)];
    __syncthreads();

    const int lane = tid & 63;
    const int w    = tid >> 6;
    const int wr   = w >> 1, wc = w & 1;     // wave quadrant: rows wr*64, cols wc*64
    const int colg = lane & 15;              // fragment col / A,B row-in-frag
    const int rowg = lane >> 4;              // k-group; D row group

    f32x4 acc[4][4];
    #pragma unroll
    for (int m = 0; m < 4; ++m)
        #pragma unroll
        for (int n = 0; n < 4; ++n)
            acc[m][n] = (f32x4){0.f, 0.f, 0.f, 0.f};

    #pragma unroll
    for (int kk = 0; kk < 4; ++kk) {
        bf16x8 af[4], bfr[4];
        #pragma unroll
        for (int m = 0; m < 4; ++m) {
            int r = wr * 64 + m * 16 + colg;
            int slot = (kk * 4 + rowg) ^ (r & 7);
            af[m] = *reinterpret_cast<const bf16x8*>(&sA[r * 128 + slot * 8]);
        }
        #pragma unroll
        for (int n = 0; n < 4; ++n) {
            int r = wc * 64 + n * 16 + colg;
            int slot = (kk * 4 + rowg) ^ (r & 7);
            bfr[n] = *reinterpret_cast<const bf16x8*>(&sB[r * 128 + slot * 8]);
        }
        #pragma unroll
        for (int m = 0; m < 4; ++m)
            #pragma unroll
            for (int n = 0; n < 4; ++n)
                acc[m][n] = __builtin_amdgcn_mfma_f32_16x16x32_bf16(af[m], bfr[n], acc[m][n], 0, 0, 0);
    }

    // ---- fused epilogue ----
    // D layout (m89): col = lane&15, row = (lane>>4)*4 + j
    int tb[4], ta[4][4];
    #pragma unroll
    for (int n = 0; n < 4; ++n) tb[n] = sTb[wc * 64 + n * 16 + colg];
    #pragma unroll
    for (int m = 0; m < 4; ++m)
        #pragma unroll
        for (int j = 0; j < 4; ++j)
            ta[m][j] = sTa[wr * 64 + m * 16 + rowg * 4 + j];

    float rE[4][4] = {{0.f}}, rQ[4][4] = {{0.f}};
    float cE[4] = {0.f, 0.f, 0.f, 0.f}, cQ[4] = {0.f, 0.f, 0.f, 0.f};

    #pragma unroll
    for (int m = 0; m < 4; ++m)
        #pragma unroll
        for (int n = 0; n < 4; ++n)
            #pragma unroll
            for (int j = 0; j < 4; ++j) {
                float d = acc[m][n][j];
                float s = T * d;
                float e = __expf(s - T);       // s <= ~T (unit-norm features): no overflow
                rE[m][j] += e;  cE[n] += e;
                if (ta[m][j] == tb[n]) { rQ[m][j] += s; cQ[n] += s; }
            }

    // row reductions: sum over 16 cols = lane bits 0..3
    #pragma unroll
    for (int m = 0; m < 4; ++m)
        #pragma unroll
        for (int j = 0; j < 4; ++j) {
            float e = rE[m][j], q = rQ[m][j];
            #pragma unroll
            for (int off = 1; off < 16; off <<= 1) {
                e += __shfl_xor(e, off);
                q += __shfl_xor(q, off);
            }
            if (colg == 0) {
                int row = brow + wr * 64 + m * 16 + rowg * 4 + j;
                atomicAdd(&rowE_g[row], e);
                atomicAdd(&rowQ_g[row], q);
            }
        }

    // col reductions: sum over 4 row-groups = lane bits 4..5 (j already folded in-lane)
    #pragma unroll
    for (int n = 0; n < 4; ++n) {
        float e = cE[n], q = cQ[n];
        e += __shfl_xor(e, 16); q += __shfl_xor(q, 16);
        e += __shfl_xor(e, 32); q += __shfl_xor(q, 32);
        if (rowg == 0) {
            int col = bcol + wc * 64 + n * 16 + colg;
            atomicAdd(&colE_g[col], e);
            atomicAdd(&colQ_g[col], q);
        }
    }
}

__global__ __launch_bounds__(256) void finalize_kernel(
    const float* __restrict__ Tptr, const int* __restrict__ targets,
    const int* __restrict__ hist,
    const float* __restrict__ rowE, const float* __restrict__ rowQ,
    const float* __restrict__ colE, const float* __restrict__ colQ,
    float* __restrict__ out)
{
    __shared__ float red[4];
    const int tid = threadIdx.x;
    int i = blockIdx.x * 256 + tid;            // 0..16383
    const float T = Tptr[0];
    int idx = i & (CN - 1);
    bool isCol = i >= CN;
    float se = isCol ? colE[idx] : rowE[idx];
    float qs = isCol ? colQ[idx] : rowQ[idx];
    float ts = (float)hist[targets[idx]];
    // per_row = -sum(eq*logits)/tsum + T + log(sum exp(s-T))
    float v = -qs / ts + T + logf(se);

    #pragma unroll
    for (int off = 1; off < 64; off <<= 1) v += __shfl_xor(v, off);
    if ((tid & 63) == 0) red[tid >> 6] = v;
    __syncthreads();
    if (tid == 0) {
        float tot = red[0] + red[1] + red[2] + red[3];
        atomicAdd(out, tot * (1.0f / (2.0f * (float)CN)));
    }
}

extern "C" void kernel_launch(void* const* d_in, const int* in_sizes, int n_in,
                              void* d_out, int out_size, void* d_ws, size_t ws_size,
                              hipStream_t stream) {
    const float* T  = (const float*)d_in[0];
    const float* fa = (const float*)d_in[1];
    const float* fb = (const float*)d_in[2];
    const int* tgt  = (const int*)d_in[3];
    float* out      = (float*)d_out;

    char* ws = (char*)d_ws;
    unsigned short* Abf = (unsigned short*)ws;
    unsigned short* Bbf = (unsigned short*)(ws + WS_B_OFF);
    int*   hist = (int*)(ws + WS_HIST_OFF);
    float* rowE = (float*)(ws + WS_ROWE_OFF);
    float* rowQ = (float*)(ws + WS_ROWQ_OFF);
    float* colE = (float*)(ws + WS_COLE_OFF);
    float* colQ = (float*)(ws + WS_COLQ_OFF);

    hipMemsetAsync(out, 0, sizeof(float), stream);
    hipMemsetAsync(ws + WS_HIST_OFF, 0, WS_ZERO_BYTES, stream);

    convert_kernel<<<dim3(CN * CD / (256 * 4), 2), 256, 0, stream>>>(fa, fb, Abf, Bbf);
    hist_kernel<<<CN / 256, 256, 0, stream>>>(tgt, hist);

    dim3 grid(CN / 128, CN / 128);
    tile_kernel<<<grid, 256, 0, stream>>>(T, Abf, Bbf, tgt, rowE, rowQ, colE, colQ);

    finalize_kernel<<<2 * CN / 256, 256, 0, stream>>>(T, tgt, hist, rowE, rowQ, colE, colQ, out);
}